// Round 6
// baseline (1643.063 us; speedup 1.0000x reference)
//
#include <hip/hip_runtime.h>
#include <hip/hip_bf16.h>
#include <math.h>

// ActorGNN R6: fully atomic-free binning (count-matrix + scans), bucket-level
// direct aggregation in LDS (float LDS atomics, no CSR), register-MLP.
// N=100000, E=3200000, G=64. Buckets: dst>>8, NB=391. Chunks: 4096 edges.

#define THREADS 256
#define BSH 8
#define MAXNB 512
#define CH_E 4096

// ---- bf16 helpers ----
__device__ inline unsigned short f2bf(float f) {
    unsigned int u = __float_as_uint(f);
    return (unsigned short)((u + 0x7fffu + ((u >> 16) & 1u)) >> 16);  // RNE
}
__device__ inline unsigned int pk2bf(float a, float b) {
    return (unsigned int)f2bf(a) | ((unsigned int)f2bf(b) << 16);
}
__device__ inline float bflo(unsigned int u) { return __uint_as_float(u << 16); }
__device__ inline float bfhi(unsigned int u) { return __uint_as_float(u & 0xffff0000u); }

// Pass A: per-chunk LDS histogram of dst buckets; record each edge's local
// position (lp16); write count row to cnt_mat[bucket][chunk]. NO global atomics.
__global__ void k_countA(const int* __restrict__ dst, unsigned short* __restrict__ lp16,
                         int* __restrict__ cnt_mat, int E, int NB, int NCH) {
    __shared__ int hist[MAXNB];
    int t = threadIdx.x, chunk = blockIdx.x;
    for (int h = t; h < NB; h += THREADS) hist[h] = 0;
    __syncthreads();
    int e0 = chunk * CH_E, e1 = min(E, e0 + CH_E);
    for (int e = e0 + t; e < e1; e += THREADS) {
        int h = dst[e] >> BSH;
        int lp = atomicAdd(&hist[h], 1);       // LDS atomic w/ return
        lp16[e] = (unsigned short)lp;          // < CH_E = 4096
    }
    __syncthreads();
    for (int h = t; h < NB; h += THREADS) cnt_mat[(size_t)h * NCH + chunk] = hist[h];
}

// K1: bucket totals (reduce cnt_mat row)
__global__ void k_sumK1(const int* __restrict__ cnt_mat, int* __restrict__ bucket_tot, int NCH) {
    __shared__ int red[THREADS];
    int b = blockIdx.x, t = threadIdx.x;
    int s = 0;
    for (int c = t; c < NCH; c += THREADS) s += cnt_mat[(size_t)b * NCH + c];
    red[t] = s;
    __syncthreads();
    for (int off = THREADS / 2; off > 0; off >>= 1) {
        if (t < off) red[t] += red[t + off];
        __syncthreads();
    }
    if (t == 0) bucket_tot[b] = red[0];
}

// K2: single block exclusive scan of NB bucket totals -> bucket_base; [NB]=E
__global__ void k_scanK2(const int* __restrict__ bucket_tot, int* __restrict__ bucket_base,
                         int NB, int E) {
    __shared__ int sh[MAXNB];
    int t = threadIdx.x;  // 512
    int v = (t < NB) ? bucket_tot[t] : 0;
    sh[t] = v;
    __syncthreads();
    for (int off = 1; off < MAXNB; off <<= 1) {
        int u = (t >= off) ? sh[t - off] : 0;
        __syncthreads();
        sh[t] += u;
        __syncthreads();
    }
    if (t < NB) bucket_base[t] = sh[t] - v;
    if (t == 0) bucket_base[NB] = E;
}

// K3: per-bucket exclusive scan over chunks + bucket base -> offs_mat
__global__ void k_scanK3(const int* __restrict__ cnt_mat, const int* __restrict__ bucket_base,
                         int* __restrict__ offs_mat, int NCH) {
    __shared__ int sh[THREADS];
    int b = blockIdx.x, t = threadIdx.x;
    const int CPT = 4;  // NCH <= 1024
    int c0 = t * CPT;
    int v[CPT];
    int s = 0;
#pragma unroll
    for (int k = 0; k < CPT; ++k) {
        int c = c0 + k;
        v[k] = (c < NCH) ? cnt_mat[(size_t)b * NCH + c] : 0;
        s += v[k];
    }
    sh[t] = s;
    __syncthreads();
    for (int off = 1; off < THREADS; off <<= 1) {
        int u = (t >= off) ? sh[t - off] : 0;
        __syncthreads();
        sh[t] += u;
        __syncthreads();
    }
    int run = bucket_base[b] + sh[t] - s;
#pragma unroll
    for (int k = 0; k < CPT; ++k) {
        int c = c0 + k;
        if (c < NCH) { offs_mat[(size_t)b * NCH + c] = run; run += v[k]; }
    }
}

// Pass B: deterministic scatter. pos = offs[bucket][chunk] + lp. No atomics.
__global__ void k_scatter2(const int* __restrict__ src, const int* __restrict__ dst,
                           const unsigned short* __restrict__ lp16,
                           const int* __restrict__ offs_mat,
                           unsigned int* __restrict__ bedges, int E, int NB, int NCH) {
    __shared__ int offs[MAXNB];
    int t = threadIdx.x, chunk = blockIdx.x;
    for (int h = t; h < NB; h += THREADS) offs[h] = offs_mat[(size_t)h * NCH + chunk];
    __syncthreads();
    int e0 = chunk * CH_E, e1 = min(E, e0 + CH_E);
    for (int e = e0 + t; e < e1; e += THREADS) {
        int d = dst[e];
        int h = d >> BSH;
        int pos = offs[h] + (int)lp16[e];
        bedges[pos] = ((unsigned int)src[e] << BSH) | (unsigned int)(d & ((1 << BSH) - 1));
    }
}

// Degrees from bucket-sorted edges: LDS per-node int histogram
__global__ void k_deg(const unsigned int* __restrict__ bedges, const int* __restrict__ bucket_base,
                      float* __restrict__ dinv, int N) {
    __shared__ int hist[THREADS];
    int t = threadIdx.x, b = blockIdx.x;
    hist[t] = 0;
    __syncthreads();
    int base = bucket_base[b], end = bucket_base[b + 1];
    for (int i = base + t; i < end; i += THREADS)
        atomicAdd(&hist[bedges[i] & (THREADS - 1)], 1);
    __syncthreads();
    int node = (b << BSH) + t;
    if (node < N) dinv[node] = (float)(1.0 / sqrt((double)(hist[t] + 1)));
}

// Hb1[n][j] = bf16( (sum_k X[n][k] * W1[k][j]) * dinv[n] )   (K=128, J=16)
__global__ void k_gemm1(const float* __restrict__ X, const float* __restrict__ W,
                        const float* __restrict__ dinv, unsigned short* __restrict__ H, int N) {
    __shared__ float Ws[128 * 16];
    for (int i = threadIdx.x; i < 128 * 16; i += blockDim.x) Ws[i] = W[i];
    __syncthreads();
    int row = blockIdx.x * 16 + threadIdx.x / 16;
    int j = threadIdx.x % 16;
    if (row >= N) return;
    const float4* xr4 = (const float4*)(X + (size_t)row * 128);
    float acc = 0.0f;
#pragma unroll
    for (int k4 = 0; k4 < 32; ++k4) {
        float4 xv = xr4[k4];
        acc += xv.x * Ws[(k4 * 4 + 0) * 16 + j];
        acc += xv.y * Ws[(k4 * 4 + 1) * 16 + j];
        acc += xv.z * Ws[(k4 * 4 + 2) * 16 + j];
        acc += xv.w * Ws[(k4 * 4 + 3) * 16 + j];
    }
    H[(size_t)row * 16 + j] = f2bf(acc * dinv[row]);
}

// Bucket-level aggregation: block = bucket. agg[f][256] in LDS (f-major:
// bank = node%32, random nodes -> ~2-way, free). Per edge: gather bf16 row,
// LDS float atomic adds. Then finalize: t = dinv*(agg + self).
// MODE 0: fp32 out = t + bias      MODE 1: bf16 out = relu(t+bias)*dinv
// MODE 2: fp32 out = t
template<int F, int MODE>
__global__ void k_agg(const unsigned int* __restrict__ bedges, const int* __restrict__ bucket_base,
                      const float* __restrict__ dinv, const unsigned short* __restrict__ Hb,
                      const float* __restrict__ bias, void* __restrict__ outp, int N) {
    __shared__ float agg[F * THREADS];
    int t = threadIdx.x, b = blockIdx.x;
    for (int i = t; i < F * THREADS; i += THREADS) agg[i] = 0.0f;
    __syncthreads();
    int base = bucket_base[b], end = bucket_base[b + 1];
    for (int i = base + t; i < end; i += THREADS) {
        unsigned int u = bedges[i];
        int d = (int)(u & (THREADS - 1));
        int s = (int)(u >> BSH);
        const uint4* row = (const uint4*)(Hb + (size_t)s * F);
#pragma unroll
        for (int q = 0; q < F / 8; ++q) {
            uint4 r = row[q];
            atomicAdd(&agg[(q * 8 + 0) * THREADS + d], bflo(r.x));
            atomicAdd(&agg[(q * 8 + 1) * THREADS + d], bfhi(r.x));
            atomicAdd(&agg[(q * 8 + 2) * THREADS + d], bflo(r.y));
            atomicAdd(&agg[(q * 8 + 3) * THREADS + d], bfhi(r.y));
            atomicAdd(&agg[(q * 8 + 4) * THREADS + d], bflo(r.z));
            atomicAdd(&agg[(q * 8 + 5) * THREADS + d], bfhi(r.z));
            atomicAdd(&agg[(q * 8 + 6) * THREADS + d], bflo(r.w));
            atomicAdd(&agg[(q * 8 + 7) * THREADS + d], bfhi(r.w));
        }
    }
    __syncthreads();
    int node = (b << BSH) + t;
    if (node >= N) return;
    float di = dinv[node];
    const uint4* srow = (const uint4*)(Hb + (size_t)node * F);
#pragma unroll
    for (int q = 0; q < F / 8; ++q) {
        uint4 r = srow[q];
        float sf[8] = { bflo(r.x), bfhi(r.x), bflo(r.y), bfhi(r.y),
                        bflo(r.z), bfhi(r.z), bflo(r.w), bfhi(r.w) };
        float v[8];
#pragma unroll
        for (int j = 0; j < 8; ++j)
            v[j] = di * (agg[(q * 8 + j) * THREADS + t] + sf[j]);
        if (MODE == 0) {
            float* of = (float*)outp + (size_t)node * F + q * 8;
#pragma unroll
            for (int j = 0; j < 8; ++j) of[j] = v[j] + bias[q * 8 + j];
        } else if (MODE == 1) {
            float w[8];
#pragma unroll
            for (int j = 0; j < 8; ++j) w[j] = fmaxf(v[j] + bias[q * 8 + j], 0.0f) * di;
            uint4 st;
            st.x = pk2bf(w[0], w[1]); st.y = pk2bf(w[2], w[3]);
            st.z = pk2bf(w[4], w[5]); st.w = pk2bf(w[6], w[7]);
            ((uint4*)((unsigned short*)outp + (size_t)node * F))[q] = st;
        } else {
            float* of = (float*)outp + (size_t)node * F + q * 8;
#pragma unroll
            for (int j = 0; j < 8; ++j) of[j] = v[j];
        }
    }
}

// Register MLP: one thread per node. Hb3[n] = bf16((relu(P2[n]@W2+b2)@W3)*dinv[n])
__global__ __launch_bounds__(256) void k_mlp(const float* __restrict__ P2,
                      const float* __restrict__ W2, const float* __restrict__ b2,
                      const float* __restrict__ W3, const float* __restrict__ dinv,
                      unsigned short* __restrict__ Hb3, int N) {
    __shared__ float W2t[64][16];   // W2t[j][k] = W2[k][j]
    __shared__ float W3t[32][64];   // W3t[m][j] = W3[j][m]
    __shared__ float b2s[64];
    int t = threadIdx.x;
    for (int i = t; i < 64 * 16; i += THREADS) W2t[i / 16][i % 16] = W2[(i % 16) * 64 + (i / 16)];
    for (int i = t; i < 32 * 64; i += THREADS) W3t[i / 64][i % 64] = W3[(i % 64) * 32 + (i / 64)];
    if (t < 64) b2s[t] = b2[t];
    __syncthreads();
    int n = blockIdx.x * THREADS + t;
    if (n >= N) return;
    const float4* pr = (const float4*)(P2 + (size_t)n * 16);
    float4 p0 = pr[0], p1 = pr[1], p2v = pr[2], p3 = pr[3];
    float p[16] = { p0.x, p0.y, p0.z, p0.w, p1.x, p1.y, p1.z, p1.w,
                    p2v.x, p2v.y, p2v.z, p2v.w, p3.x, p3.y, p3.z, p3.w };
    float a[64];
#pragma unroll
    for (int j = 0; j < 64; ++j) {
        const float4* w = (const float4*)W2t[j];  // wave-uniform -> LDS broadcast
        float4 w0 = w[0], w1 = w[1], w2q = w[2], w3q = w[3];
        float acc = b2s[j];
        acc += p[0] * w0.x + p[1] * w0.y + p[2] * w0.z + p[3] * w0.w;
        acc += p[4] * w1.x + p[5] * w1.y + p[6] * w1.z + p[7] * w1.w;
        acc += p[8] * w2q.x + p[9] * w2q.y + p[10] * w2q.z + p[11] * w2q.w;
        acc += p[12] * w3q.x + p[13] * w3q.y + p[14] * w3q.z + p[15] * w3q.w;
        a[j] = fmaxf(acc, 0.0f);
    }
    float di = dinv[n];
    unsigned short* outr = Hb3 + (size_t)n * 32;
#pragma unroll
    for (int m = 0; m < 32; m += 2) {
        float o0 = 0.0f, o1 = 0.0f;
        const float4* wa = (const float4*)W3t[m];
        const float4* wb = (const float4*)W3t[m + 1];
#pragma unroll
        for (int q = 0; q < 16; ++q) {
            float4 va = wa[q], vb = wb[q];
            o0 += a[4 * q] * va.x + a[4 * q + 1] * va.y + a[4 * q + 2] * va.z + a[4 * q + 3] * va.w;
            o1 += a[4 * q] * vb.x + a[4 * q + 1] * vb.y + a[4 * q + 2] * vb.z + a[4 * q + 3] * vb.w;
        }
        *(unsigned int*)(outr + m) = pk2bf(o0 * di, o1 * di);
    }
}

// batch sorted: block g binary-searches its node range, mean over 32 features
__global__ void k_pool_mean(const float* __restrict__ h, const int* __restrict__ batch,
                            int N, float* __restrict__ pooled) {
    int g = blockIdx.x;
    int lo = 0, hi = N;
    while (lo < hi) { int m = (lo + hi) >> 1; if (batch[m] < g) lo = m + 1; else hi = m; }
    int start = lo;
    lo = start; hi = N;
    while (lo < hi) { int m = (lo + hi) >> 1; if (batch[m] < g + 1) lo = m + 1; else hi = m; }
    int end = lo;

    __shared__ float partial[THREADS];
    int f = threadIdx.x % 32;
    int grp = threadIdx.x / 32;
    float acc = 0.0f;
    for (int n = start + grp; n < end; n += 8) acc += h[(size_t)n * 32 + f];
    partial[threadIdx.x] = acc;
    __syncthreads();
    if (threadIdx.x < 32) {
        float s = 0.0f;
#pragma unroll
        for (int tt = 0; tt < 8; ++tt) s += partial[tt * 32 + f];
        int cnt = end - start;
        pooled[g * 32 + f] = s / (float)(cnt > 0 ? cnt : 1);
    }
}

// a = relu(pooled @ Wa + ba) [G,64]; out = tanh(a @ Wo + bo) [G,32]
__global__ void k_head(const float* __restrict__ pooled, const float* __restrict__ Wa,
                       const float* __restrict__ ba, const float* __restrict__ Wo,
                       const float* __restrict__ bo, float* __restrict__ out) {
    int g = blockIdx.x;
    int j = threadIdx.x;  // 64 threads
    __shared__ float p[32];
    __shared__ float a[64];
    if (j < 32) p[j] = pooled[g * 32 + j];
    __syncthreads();
    float acc = ba[j];
#pragma unroll
    for (int k = 0; k < 32; ++k) acc += p[k] * Wa[k * 64 + j];
    a[j] = fmaxf(acc, 0.0f);
    __syncthreads();
    if (j < 32) {
        float acc2 = bo[j];
#pragma unroll
        for (int k = 0; k < 64; ++k) acc2 += a[k] * Wo[k * 32 + j];
        out[g * 32 + j] = tanhf(acc2);
    }
}

static inline int cdiv(long long a, int b) { return (int)((a + b - 1) / b); }
static inline size_t align256(size_t x) { return (x + 255) & ~(size_t)255; }

extern "C" void kernel_launch(void* const* d_in, const int* in_sizes, int n_in,
                              void* d_out, int out_size, void* d_ws, size_t ws_size,
                              hipStream_t stream) {
    const float* x     = (const float*)d_in[0];
    const int*   edge  = (const int*)d_in[1];
    const int*   batch = (const int*)d_in[2];
    const float* W1 = (const float*)d_in[3];  const float* b1 = (const float*)d_in[4];
    const float* W2 = (const float*)d_in[5];  const float* b2 = (const float*)d_in[6];
    const float* W3 = (const float*)d_in[7];  const float* b3 = (const float*)d_in[8];
    const float* Wa = (const float*)d_in[9];  const float* ba = (const float*)d_in[10];
    const float* Wo = (const float*)d_in[11]; const float* bo = (const float*)d_in[12];

    const int E = in_sizes[1] / 2;
    const int N = in_sizes[2];
    const int G = 64;
    const int NB = cdiv(N, 1 << BSH);     // 391
    const int NCH = cdiv(E, CH_E);        // 782

    const int* srcp = edge;
    const int* dstp = edge + E;

    // Workspace
    char* base = (char*)d_ws;
    size_t off = 0;
    float* dinv   = (float*)(base + off); off = align256(off + sizeof(float) * N);
    unsigned short* lp16 = (unsigned short*)(base + off); off = align256(off + sizeof(short) * E);
    int* cnt_mat  = (int*)(base + off); off = align256(off + sizeof(int) * (size_t)NB * NCH);
    int* offs_mat = (int*)(base + off); off = align256(off + sizeof(int) * (size_t)NB * NCH);
    int* btot     = (int*)(base + off); off = align256(off + sizeof(int) * (NB + 1));
    int* bbase    = (int*)(base + off); off = align256(off + sizeof(int) * (NB + 1));
    unsigned int* bedges = (unsigned int*)(base + off); off = align256(off + sizeof(int) * E);
    unsigned short* Hb1 = (unsigned short*)(base + off); off = align256(off + sizeof(short) * (size_t)N * 16);
    unsigned short* Hb2 = (unsigned short*)(base + off); off = align256(off + sizeof(short) * (size_t)N * 16);
    float* P2     = (float*)(base + off); off = align256(off + sizeof(float) * (size_t)N * 16);
    unsigned short* Hb3 = (unsigned short*)(base + off); off = align256(off + sizeof(short) * (size_t)N * 32);
    float* h3     = (float*)(base + off); off = align256(off + sizeof(float) * (size_t)N * 32);
    float* pooled = (float*)(base + off); off = align256(off + sizeof(float) * G * 32);

    // ---- Atomic-free binning ----
    k_countA<<<NCH, THREADS, 0, stream>>>(dstp, lp16, cnt_mat, E, NB, NCH);
    k_sumK1<<<NB, THREADS, 0, stream>>>(cnt_mat, btot, NCH);
    k_scanK2<<<1, MAXNB, 0, stream>>>(btot, bbase, NB, E);
    k_scanK3<<<NB, THREADS, 0, stream>>>(cnt_mat, bbase, offs_mat, NCH);
    k_scatter2<<<NCH, THREADS, 0, stream>>>(srcp, dstp, lp16, offs_mat, bedges, E, NB, NCH);
    k_deg<<<NB, THREADS, 0, stream>>>(bedges, bbase, dinv, N);

    // ---- Layer 1 ----
    k_gemm1<<<cdiv(N, 16), THREADS, 0, stream>>>(x, W1, dinv, Hb1, N);
    k_agg<16, 1><<<NB, THREADS, 0, stream>>>(bedges, bbase, dinv, Hb1, b1, Hb2, N);

    // ---- Layer 2 aggregate at input width ----
    k_agg<16, 2><<<NB, THREADS, 0, stream>>>(bedges, bbase, dinv, Hb2, b1 /*unused*/, P2, N);

    // ---- Fused node MLP ----
    k_mlp<<<cdiv(N, THREADS), THREADS, 0, stream>>>(P2, W2, b2, W3, dinv, Hb3, N);

    // ---- Layer 3 aggregate ----
    k_agg<32, 0><<<NB, THREADS, 0, stream>>>(bedges, bbase, dinv, Hb3, b3, h3, N);

    // ---- Pool + head ----
    k_pool_mean<<<G, THREADS, 0, stream>>>(h3, batch, N, pooled);
    k_head<<<G, 64, 0, stream>>>(pooled, Wa, ba, Wo, bo, (float*)d_out);
}

// Round 7
// 415.161 us; speedup vs baseline: 3.9577x; 3.9577x over previous
//
#include <hip/hip_runtime.h>
#include <hip/hip_bf16.h>
#include <math.h>

// ActorGNN R7: R5 backbone (CSR + bf16 unrolled pulls) + R6's register-MLP and
// atomic-free binning (count-matrix + scans, CH_E=2048).
// N=100000, E=3200000, G=64. Layers 128->16->64->32, pool, head 32->64->32.

#define THREADS 256
#define BSH 8                 // bucket shift: bucket = dst>>8 (<=256 nodes each)
#define MAXNB 512             // LDS histogram capacity (N <= 131072)
#define CH_E 2048             // edges per chunk in binning passes
#define CPT 8                 // chunks per thread in k_scanK3 (NCH <= 2048)

// ---- bf16 helpers ----
__device__ inline unsigned short f2bf(float f) {
    unsigned int u = __float_as_uint(f);
    return (unsigned short)((u + 0x7fffu + ((u >> 16) & 1u)) >> 16);  // RNE
}
__device__ inline unsigned int pk2bf(float a, float b) {
    return (unsigned int)f2bf(a) | ((unsigned int)f2bf(b) << 16);
}
__device__ inline float4 ldbf4(const unsigned short* p) {
    uint2 u = *(const uint2*)p;  // 4 bf16 = 8B
    float4 r;
    r.x = __uint_as_float(u.x << 16);
    r.y = __uint_as_float(u.x & 0xffff0000u);
    r.z = __uint_as_float(u.y << 16);
    r.w = __uint_as_float(u.y & 0xffff0000u);
    return r;
}

// ---- Atomic-free binning: pass A counts + records local position ----
__global__ void k_countA(const int* __restrict__ dst, unsigned short* __restrict__ lp16,
                         int* __restrict__ cnt_mat, int E, int NB, int NCH) {
    __shared__ int hist[MAXNB];
    int t = threadIdx.x, chunk = blockIdx.x;
    for (int h = t; h < NB; h += THREADS) hist[h] = 0;
    __syncthreads();
    int e0 = chunk * CH_E, e1 = min(E, e0 + CH_E);
    for (int e = e0 + t; e < e1; e += THREADS) {
        int h = dst[e] >> BSH;
        int lp = atomicAdd(&hist[h], 1);       // LDS atomic (cheap, low contention)
        lp16[e] = (unsigned short)lp;          // < CH_E
    }
    __syncthreads();
    for (int h = t; h < NB; h += THREADS) cnt_mat[(size_t)h * NCH + chunk] = hist[h];
}

// K1: bucket totals
__global__ void k_sumK1(const int* __restrict__ cnt_mat, int* __restrict__ bucket_tot, int NCH) {
    __shared__ int red[THREADS];
    int b = blockIdx.x, t = threadIdx.x;
    int s = 0;
    for (int c = t; c < NCH; c += THREADS) s += cnt_mat[(size_t)b * NCH + c];
    red[t] = s;
    __syncthreads();
    for (int off = THREADS / 2; off > 0; off >>= 1) {
        if (t < off) red[t] += red[t + off];
        __syncthreads();
    }
    if (t == 0) bucket_tot[b] = red[0];
}

// K2: single block exclusive scan of NB bucket totals -> bucket_base; [NB]=E
__global__ void k_scanK2(const int* __restrict__ bucket_tot, int* __restrict__ bucket_base,
                         int NB, int E) {
    __shared__ int sh[MAXNB];
    int t = threadIdx.x;  // 512
    int v = (t < NB) ? bucket_tot[t] : 0;
    sh[t] = v;
    __syncthreads();
    for (int off = 1; off < MAXNB; off <<= 1) {
        int u = (t >= off) ? sh[t - off] : 0;
        __syncthreads();
        sh[t] += u;
        __syncthreads();
    }
    if (t < NB) bucket_base[t] = sh[t] - v;
    if (t == 0) bucket_base[NB] = E;
}

// K3: per-bucket exclusive scan over chunks + bucket base -> offs_mat
__global__ void k_scanK3(const int* __restrict__ cnt_mat, const int* __restrict__ bucket_base,
                         int* __restrict__ offs_mat, int NCH) {
    __shared__ int sh[THREADS];
    int b = blockIdx.x, t = threadIdx.x;
    int c0 = t * CPT;
    int v[CPT];
    int s = 0;
#pragma unroll
    for (int k = 0; k < CPT; ++k) {
        int c = c0 + k;
        v[k] = (c < NCH) ? cnt_mat[(size_t)b * NCH + c] : 0;
        s += v[k];
    }
    sh[t] = s;
    __syncthreads();
    for (int off = 1; off < THREADS; off <<= 1) {
        int u = (t >= off) ? sh[t - off] : 0;
        __syncthreads();
        sh[t] += u;
        __syncthreads();
    }
    int run = bucket_base[b] + sh[t] - s;
#pragma unroll
    for (int k = 0; k < CPT; ++k) {
        int c = c0 + k;
        if (c < NCH) { offs_mat[(size_t)b * NCH + c] = run; run += v[k]; }
    }
}

// Pass B: deterministic scatter. pos = offs[bucket][chunk] + lp. No atomics.
__global__ void k_scatter2(const int* __restrict__ src, const int* __restrict__ dst,
                           const unsigned short* __restrict__ lp16,
                           const int* __restrict__ offs_mat,
                           unsigned int* __restrict__ bedges, int E, int NB, int NCH) {
    __shared__ int offs[MAXNB];
    int t = threadIdx.x, chunk = blockIdx.x;
    for (int h = t; h < NB; h += THREADS) offs[h] = offs_mat[(size_t)h * NCH + chunk];
    __syncthreads();
    int e0 = chunk * CH_E, e1 = min(E, e0 + CH_E);
    for (int e = e0 + t; e < e1; e += THREADS) {
        int d = dst[e];
        int h = d >> BSH;
        int pos = offs[h] + (int)lp16[e];
        bedges[pos] = ((unsigned int)src[e] << BSH) | (unsigned int)(d & ((1 << BSH) - 1));
    }
}

// Block = bucket (<=256 nodes): LDS histogram -> rowptr, dinv; place srcs into csr_src.
__global__ void k_bucket_csr(const unsigned int* __restrict__ bedges,
                             const int* __restrict__ bucket_base,
                             int* __restrict__ rowptr, float* __restrict__ dinv,
                             int* __restrict__ csr_src, int N) {
    __shared__ int hist[THREADS];
    __shared__ int sc[THREADS];
    __shared__ int cur[THREADS];
    int t = threadIdx.x;
    int b = blockIdx.x;
    int base = bucket_base[b];
    int end = bucket_base[b + 1];
    hist[t] = 0;
    __syncthreads();
    for (int i = base + t; i < end; i += THREADS)
        atomicAdd(&hist[bedges[i] & (THREADS - 1)], 1);
    __syncthreads();
    int c = hist[t];
    sc[t] = c;
    __syncthreads();
    for (int off = 1; off < THREADS; off <<= 1) {
        int u = (t >= off) ? sc[t - off] : 0;
        __syncthreads();
        sc[t] += u;
        __syncthreads();
    }
    int excl = sc[t] - c;
    int node = (b << BSH) + t;
    if (node < N) {
        rowptr[node] = base + excl;
        dinv[node] = (float)(1.0 / sqrt((double)(c + 1)));
    }
    cur[t] = excl;
    __syncthreads();
    for (int i = base + t; i < end; i += THREADS) {
        unsigned int u = bedges[i];
        int ln = (int)(u & (THREADS - 1));
        int p = atomicAdd(&cur[ln], 1);
        csr_src[base + p] = (int)(u >> BSH);
    }
}

// Hb1[n][j] = bf16( (sum_k X[n][k] * W1[k][j]) * dinv[n] )   (K=128, J=16)
__global__ void k_gemm1(const float* __restrict__ X, const float* __restrict__ W,
                        const float* __restrict__ dinv, unsigned short* __restrict__ H, int N) {
    __shared__ float Ws[128 * 16];
    for (int i = threadIdx.x; i < 128 * 16; i += blockDim.x) Ws[i] = W[i];
    __syncthreads();
    int row = blockIdx.x * 16 + threadIdx.x / 16;
    int j = threadIdx.x % 16;
    if (row >= N) return;
    const float4* xr4 = (const float4*)(X + (size_t)row * 128);
    float acc = 0.0f;
#pragma unroll
    for (int k4 = 0; k4 < 32; ++k4) {
        float4 xv = xr4[k4];
        acc += xv.x * Ws[(k4 * 4 + 0) * 16 + j];
        acc += xv.y * Ws[(k4 * 4 + 1) * 16 + j];
        acc += xv.z * Ws[(k4 * 4 + 2) * 16 + j];
        acc += xv.w * Ws[(k4 * 4 + 3) * 16 + j];
    }
    H[(size_t)row * 16 + j] = f2bf(acc * dinv[row]);
}

// Pull from bf16 table: t = dinv[n]*(sum_{e->n} Hb[src] + Hb[n]); 4 features/lane.
// MODE 0: fp32 out = t + b          (final layer, pre-pool)
// MODE 1: bf16 out = relu(t+b)*dinv (L1 out, pre-scaled for next pull)
// MODE 2: fp32 out = t              (L2 pre-GEMM aggregate)
template<int F, int MODE>
__global__ void k_pull(const int* __restrict__ rowptr, const int* __restrict__ csr_src,
                       const float* __restrict__ dinv, const unsigned short* __restrict__ Hb,
                       const float* __restrict__ bias, void* __restrict__ outp, int N) {
    const int LPN = F / 4;             // lanes per node
    const int NPB = THREADS / LPN;     // nodes per block
    int node = blockIdx.x * NPB + threadIdx.x / LPN;
    int fq = threadIdx.x % LPN;        // feature quad
    if (node >= N) return;
    int beg = rowptr[node], end = rowptr[node + 1];
    const size_t off = (size_t)4 * fq;
    float4 acc = make_float4(0.f, 0.f, 0.f, 0.f);
    int i = beg;
    for (; i + 4 <= end; i += 4) {
        int s0 = csr_src[i + 0];
        int s1 = csr_src[i + 1];
        int s2 = csr_src[i + 2];
        int s3 = csr_src[i + 3];
        float4 g0 = ldbf4(Hb + (size_t)s0 * F + off);
        float4 g1 = ldbf4(Hb + (size_t)s1 * F + off);
        float4 g2 = ldbf4(Hb + (size_t)s2 * F + off);
        float4 g3 = ldbf4(Hb + (size_t)s3 * F + off);
        acc.x += (g0.x + g1.x) + (g2.x + g3.x);
        acc.y += (g0.y + g1.y) + (g2.y + g3.y);
        acc.z += (g0.z + g1.z) + (g2.z + g3.z);
        acc.w += (g0.w + g1.w) + (g2.w + g3.w);
    }
    for (; i < end; ++i) {
        int s = csr_src[i];
        float4 g = ldbf4(Hb + (size_t)s * F + off);
        acc.x += g.x; acc.y += g.y; acc.z += g.z; acc.w += g.w;
    }
    float4 self = ldbf4(Hb + (size_t)node * F + off);
    float di = dinv[node];
    float4 t;
    t.x = di * (acc.x + self.x);
    t.y = di * (acc.y + self.y);
    t.z = di * (acc.z + self.z);
    t.w = di * (acc.w + self.w);
    if (MODE == 0) {
        float4 o;
        o.x = t.x + bias[4 * fq + 0];
        o.y = t.y + bias[4 * fq + 1];
        o.z = t.z + bias[4 * fq + 2];
        o.w = t.w + bias[4 * fq + 3];
        *(float4*)((float*)outp + (size_t)node * F + off) = o;
    } else if (MODE == 1) {
        float4 v;
        v.x = fmaxf(t.x + bias[4 * fq + 0], 0.f) * di;
        v.y = fmaxf(t.y + bias[4 * fq + 1], 0.f) * di;
        v.z = fmaxf(t.z + bias[4 * fq + 2], 0.f) * di;
        v.w = fmaxf(t.w + bias[4 * fq + 3], 0.f) * di;
        uint2 st;
        st.x = pk2bf(v.x, v.y);
        st.y = pk2bf(v.z, v.w);
        *(uint2*)((unsigned short*)outp + (size_t)node * F + off) = st;
    } else {
        *(float4*)((float*)outp + (size_t)node * F + off) = t;
    }
}

// Register MLP: one thread per node. Hb3[n] = bf16((relu(P2[n]@W2+b2)@W3)*dinv[n])
__global__ __launch_bounds__(256) void k_mlp(const float* __restrict__ P2,
                      const float* __restrict__ W2, const float* __restrict__ b2,
                      const float* __restrict__ W3, const float* __restrict__ dinv,
                      unsigned short* __restrict__ Hb3, int N) {
    __shared__ float W2t[64][16];   // W2t[j][k] = W2[k][j]
    __shared__ float W3t[32][64];   // W3t[m][j] = W3[j][m]
    __shared__ float b2s[64];
    int t = threadIdx.x;
    for (int i = t; i < 64 * 16; i += THREADS) W2t[i / 16][i % 16] = W2[(i % 16) * 64 + (i / 16)];
    for (int i = t; i < 32 * 64; i += THREADS) W3t[i / 64][i % 64] = W3[(i % 64) * 32 + (i / 64)];
    if (t < 64) b2s[t] = b2[t];
    __syncthreads();
    int n = blockIdx.x * THREADS + t;
    if (n >= N) return;
    const float4* pr = (const float4*)(P2 + (size_t)n * 16);
    float4 p0 = pr[0], p1 = pr[1], p2v = pr[2], p3 = pr[3];
    float p[16] = { p0.x, p0.y, p0.z, p0.w, p1.x, p1.y, p1.z, p1.w,
                    p2v.x, p2v.y, p2v.z, p2v.w, p3.x, p3.y, p3.z, p3.w };
    float a[64];
#pragma unroll
    for (int j = 0; j < 64; ++j) {
        const float4* w = (const float4*)W2t[j];  // wave-uniform -> LDS broadcast
        float4 w0 = w[0], w1 = w[1], w2q = w[2], w3q = w[3];
        float acc = b2s[j];
        acc += p[0] * w0.x + p[1] * w0.y + p[2] * w0.z + p[3] * w0.w;
        acc += p[4] * w1.x + p[5] * w1.y + p[6] * w1.z + p[7] * w1.w;
        acc += p[8] * w2q.x + p[9] * w2q.y + p[10] * w2q.z + p[11] * w2q.w;
        acc += p[12] * w3q.x + p[13] * w3q.y + p[14] * w3q.z + p[15] * w3q.w;
        a[j] = fmaxf(acc, 0.0f);
    }
    float di = dinv[n];
    unsigned short* outr = Hb3 + (size_t)n * 32;
#pragma unroll
    for (int m = 0; m < 32; m += 2) {
        float o0 = 0.0f, o1 = 0.0f;
        const float4* wa = (const float4*)W3t[m];
        const float4* wb = (const float4*)W3t[m + 1];
#pragma unroll
        for (int q = 0; q < 16; ++q) {
            float4 va = wa[q], vb = wb[q];
            o0 += a[4 * q] * va.x + a[4 * q + 1] * va.y + a[4 * q + 2] * va.z + a[4 * q + 3] * va.w;
            o1 += a[4 * q] * vb.x + a[4 * q + 1] * vb.y + a[4 * q + 2] * vb.z + a[4 * q + 3] * vb.w;
        }
        *(unsigned int*)(outr + m) = pk2bf(o0 * di, o1 * di);
    }
}

// batch sorted: block g binary-searches its node range, mean over 32 features
__global__ void k_pool_mean(const float* __restrict__ h, const int* __restrict__ batch,
                            int N, float* __restrict__ pooled) {
    int g = blockIdx.x;
    int lo = 0, hi = N;
    while (lo < hi) { int m = (lo + hi) >> 1; if (batch[m] < g) lo = m + 1; else hi = m; }
    int start = lo;
    lo = start; hi = N;
    while (lo < hi) { int m = (lo + hi) >> 1; if (batch[m] < g + 1) lo = m + 1; else hi = m; }
    int end = lo;

    __shared__ float partial[THREADS];
    int f = threadIdx.x % 32;
    int grp = threadIdx.x / 32;
    float acc = 0.0f;
    for (int n = start + grp; n < end; n += 8) acc += h[(size_t)n * 32 + f];
    partial[threadIdx.x] = acc;
    __syncthreads();
    if (threadIdx.x < 32) {
        float s = 0.0f;
#pragma unroll
        for (int tt = 0; tt < 8; ++tt) s += partial[tt * 32 + f];
        int cnt = end - start;
        pooled[g * 32 + f] = s / (float)(cnt > 0 ? cnt : 1);
    }
}

// a = relu(pooled @ Wa + ba) [G,64]; out = tanh(a @ Wo + bo) [G,32]
__global__ void k_head(const float* __restrict__ pooled, const float* __restrict__ Wa,
                       const float* __restrict__ ba, const float* __restrict__ Wo,
                       const float* __restrict__ bo, float* __restrict__ out) {
    int g = blockIdx.x;
    int j = threadIdx.x;  // 64 threads
    __shared__ float p[32];
    __shared__ float a[64];
    if (j < 32) p[j] = pooled[g * 32 + j];
    __syncthreads();
    float acc = ba[j];
#pragma unroll
    for (int k = 0; k < 32; ++k) acc += p[k] * Wa[k * 64 + j];
    a[j] = fmaxf(acc, 0.0f);
    __syncthreads();
    if (j < 32) {
        float acc2 = bo[j];
#pragma unroll
        for (int k = 0; k < 64; ++k) acc2 += a[k] * Wo[k * 32 + j];
        out[g * 32 + j] = tanhf(acc2);
    }
}

static inline int cdiv(long long a, int b) { return (int)((a + b - 1) / b); }
static inline size_t align256(size_t x) { return (x + 255) & ~(size_t)255; }

extern "C" void kernel_launch(void* const* d_in, const int* in_sizes, int n_in,
                              void* d_out, int out_size, void* d_ws, size_t ws_size,
                              hipStream_t stream) {
    const float* x     = (const float*)d_in[0];
    const int*   edge  = (const int*)d_in[1];
    const int*   batch = (const int*)d_in[2];
    const float* W1 = (const float*)d_in[3];  const float* b1 = (const float*)d_in[4];
    const float* W2 = (const float*)d_in[5];  const float* b2 = (const float*)d_in[6];
    const float* W3 = (const float*)d_in[7];  const float* b3 = (const float*)d_in[8];
    const float* Wa = (const float*)d_in[9];  const float* ba = (const float*)d_in[10];
    const float* Wo = (const float*)d_in[11]; const float* bo = (const float*)d_in[12];

    const int E = in_sizes[1] / 2;
    const int N = in_sizes[2];
    const int G = 64;
    const int NB = cdiv(N, 1 << BSH);     // 391
    const int NCH = cdiv(E, CH_E);        // 1563

    const int* srcp = edge;
    const int* dstp = edge + E;

    // Workspace
    char* base = (char*)d_ws;
    size_t off = 0;
    float* dinv   = (float*)(base + off); off = align256(off + sizeof(float) * N);
    unsigned short* lp16 = (unsigned short*)(base + off); off = align256(off + sizeof(short) * E);
    int* cnt_mat  = (int*)(base + off); off = align256(off + sizeof(int) * (size_t)NB * NCH);
    int* offs_mat = (int*)(base + off); off = align256(off + sizeof(int) * (size_t)NB * NCH);
    int* btot     = (int*)(base + off); off = align256(off + sizeof(int) * (NB + 1));
    int* bbase    = (int*)(base + off); off = align256(off + sizeof(int) * (NB + 1));
    unsigned int* bedges = (unsigned int*)(base + off); off = align256(off + sizeof(int) * E);
    int* rowptr   = (int*)(base + off); off = align256(off + sizeof(int) * (N + 1));
    int* csr_src  = (int*)(base + off); off = align256(off + sizeof(int) * E);
    unsigned short* Hb1 = (unsigned short*)(base + off); off = align256(off + sizeof(short) * (size_t)N * 16);
    unsigned short* Hb2 = (unsigned short*)(base + off); off = align256(off + sizeof(short) * (size_t)N * 16);
    float* P2     = (float*)(base + off); off = align256(off + sizeof(float) * (size_t)N * 16);
    unsigned short* Hb3 = (unsigned short*)(base + off); off = align256(off + sizeof(short) * (size_t)N * 32);
    float* h3     = (float*)(base + off); off = align256(off + sizeof(float) * (size_t)N * 32);
    float* pooled = (float*)(base + off); off = align256(off + sizeof(float) * G * 32);

    // ---- Atomic-free binning -> bucket-sorted bedges ----
    k_countA<<<NCH, THREADS, 0, stream>>>(dstp, lp16, cnt_mat, E, NB, NCH);
    k_sumK1<<<NB, THREADS, 0, stream>>>(cnt_mat, btot, NCH);
    k_scanK2<<<1, MAXNB, 0, stream>>>(btot, bbase, NB, E);
    k_scanK3<<<NB, THREADS, 0, stream>>>(cnt_mat, bbase, offs_mat, NCH);
    k_scatter2<<<NCH, THREADS, 0, stream>>>(srcp, dstp, lp16, offs_mat, bedges, E, NB, NCH);

    // ---- CSR (rowptr, csr_src, dinv) from bucket-sorted edges ----
    k_bucket_csr<<<NB, THREADS, 0, stream>>>(bedges, bbase, rowptr, dinv, csr_src, N);

    // ---- Layer 1: Hb1 = bf16((x@W1)*dinv); pull16 -> Hb2 = bf16(relu(.+b1)*dinv) ----
    k_gemm1<<<cdiv(N, 16), THREADS, 0, stream>>>(x, W1, dinv, Hb1, N);
    k_pull<16, 1><<<cdiv(N, 64), THREADS, 0, stream>>>(rowptr, csr_src, dinv, Hb1, b1, Hb2, N);

    // ---- Layer 2 aggregate at input width: P2 = pull16(Hb2) ----
    k_pull<16, 2><<<cdiv(N, 64), THREADS, 0, stream>>>(rowptr, csr_src, dinv, Hb2, b1 /*unused*/, P2, N);

    // ---- Fused node MLP: Hb3 = bf16((relu(P2@W2+b2)@W3)*dinv) ----
    k_mlp<<<cdiv(N, THREADS), THREADS, 0, stream>>>(P2, W2, b2, W3, dinv, Hb3, N);

    // ---- Layer 3 aggregate: h3 = pull32(Hb3) + b3 ----
    k_pull<32, 0><<<cdiv(N, 32), THREADS, 0, stream>>>(rowptr, csr_src, dinv, Hb3, b3, h3, N);

    // ---- Pool + head ----
    k_pool_mean<<<G, THREADS, 0, stream>>>(h3, batch, N, pooled);
    k_head<<<G, 64, 0, stream>>>(pooled, Wa, ba, Wo, bo, (float*)d_out);
}

// Round 8
// 392.800 us; speedup vs baseline: 4.1829x; 1.0569x over previous
//
#include <hip/hip_runtime.h>
#include <hip/hip_bf16.h>
#include <math.h>

// ActorGNN R8: R7 + parallel segmented pooling (run-length atomics) replacing
// the 64-block k_pool_mean. N=100000, E=3200000, G=64.

#define THREADS 256
#define BSH 8                 // bucket shift: bucket = dst>>8 (<=256 nodes each)
#define MAXNB 512             // LDS histogram capacity (N <= 131072)
#define CH_E 2048             // edges per chunk in binning passes
#define CPT 8                 // chunks per thread in k_scanK3 (NCH <= 2048)
#define POOL_C 512            // nodes per pooling block

// ---- bf16 helpers ----
__device__ inline unsigned short f2bf(float f) {
    unsigned int u = __float_as_uint(f);
    return (unsigned short)((u + 0x7fffu + ((u >> 16) & 1u)) >> 16);  // RNE
}
__device__ inline unsigned int pk2bf(float a, float b) {
    return (unsigned int)f2bf(a) | ((unsigned int)f2bf(b) << 16);
}
__device__ inline float4 ldbf4(const unsigned short* p) {
    uint2 u = *(const uint2*)p;  // 4 bf16 = 8B
    float4 r;
    r.x = __uint_as_float(u.x << 16);
    r.y = __uint_as_float(u.x & 0xffff0000u);
    r.z = __uint_as_float(u.y << 16);
    r.w = __uint_as_float(u.y & 0xffff0000u);
    return r;
}

// ---- Atomic-free binning: pass A counts + records local position ----
__global__ void k_countA(const int* __restrict__ dst, unsigned short* __restrict__ lp16,
                         int* __restrict__ cnt_mat, int E, int NB, int NCH) {
    __shared__ int hist[MAXNB];
    int t = threadIdx.x, chunk = blockIdx.x;
    for (int h = t; h < NB; h += THREADS) hist[h] = 0;
    __syncthreads();
    int e0 = chunk * CH_E, e1 = min(E, e0 + CH_E);
    for (int e = e0 + t; e < e1; e += THREADS) {
        int h = dst[e] >> BSH;
        int lp = atomicAdd(&hist[h], 1);       // LDS atomic (cheap, low contention)
        lp16[e] = (unsigned short)lp;          // < CH_E
    }
    __syncthreads();
    for (int h = t; h < NB; h += THREADS) cnt_mat[(size_t)h * NCH + chunk] = hist[h];
}

// K1: bucket totals
__global__ void k_sumK1(const int* __restrict__ cnt_mat, int* __restrict__ bucket_tot, int NCH) {
    __shared__ int red[THREADS];
    int b = blockIdx.x, t = threadIdx.x;
    int s = 0;
    for (int c = t; c < NCH; c += THREADS) s += cnt_mat[(size_t)b * NCH + c];
    red[t] = s;
    __syncthreads();
    for (int off = THREADS / 2; off > 0; off >>= 1) {
        if (t < off) red[t] += red[t + off];
        __syncthreads();
    }
    if (t == 0) bucket_tot[b] = red[0];
}

// K2: single block exclusive scan of NB bucket totals -> bucket_base; [NB]=E
__global__ void k_scanK2(const int* __restrict__ bucket_tot, int* __restrict__ bucket_base,
                         int NB, int E) {
    __shared__ int sh[MAXNB];
    int t = threadIdx.x;  // 512
    int v = (t < NB) ? bucket_tot[t] : 0;
    sh[t] = v;
    __syncthreads();
    for (int off = 1; off < MAXNB; off <<= 1) {
        int u = (t >= off) ? sh[t - off] : 0;
        __syncthreads();
        sh[t] += u;
        __syncthreads();
    }
    if (t < NB) bucket_base[t] = sh[t] - v;
    if (t == 0) bucket_base[NB] = E;
}

// K3: per-bucket exclusive scan over chunks + bucket base -> offs_mat
__global__ void k_scanK3(const int* __restrict__ cnt_mat, const int* __restrict__ bucket_base,
                         int* __restrict__ offs_mat, int NCH) {
    __shared__ int sh[THREADS];
    int b = blockIdx.x, t = threadIdx.x;
    int c0 = t * CPT;
    int v[CPT];
    int s = 0;
#pragma unroll
    for (int k = 0; k < CPT; ++k) {
        int c = c0 + k;
        v[k] = (c < NCH) ? cnt_mat[(size_t)b * NCH + c] : 0;
        s += v[k];
    }
    sh[t] = s;
    __syncthreads();
    for (int off = 1; off < THREADS; off <<= 1) {
        int u = (t >= off) ? sh[t - off] : 0;
        __syncthreads();
        sh[t] += u;
        __syncthreads();
    }
    int run = bucket_base[b] + sh[t] - s;
#pragma unroll
    for (int k = 0; k < CPT; ++k) {
        int c = c0 + k;
        if (c < NCH) { offs_mat[(size_t)b * NCH + c] = run; run += v[k]; }
    }
}

// Pass B: deterministic scatter. pos = offs[bucket][chunk] + lp. No atomics.
__global__ void k_scatter2(const int* __restrict__ src, const int* __restrict__ dst,
                           const unsigned short* __restrict__ lp16,
                           const int* __restrict__ offs_mat,
                           unsigned int* __restrict__ bedges, int E, int NB, int NCH) {
    __shared__ int offs[MAXNB];
    int t = threadIdx.x, chunk = blockIdx.x;
    for (int h = t; h < NB; h += THREADS) offs[h] = offs_mat[(size_t)h * NCH + chunk];
    __syncthreads();
    int e0 = chunk * CH_E, e1 = min(E, e0 + CH_E);
    for (int e = e0 + t; e < e1; e += THREADS) {
        int d = dst[e];
        int h = d >> BSH;
        int pos = offs[h] + (int)lp16[e];
        bedges[pos] = ((unsigned int)src[e] << BSH) | (unsigned int)(d & ((1 << BSH) - 1));
    }
}

// Block = bucket (<=256 nodes): LDS histogram -> rowptr, dinv; place srcs into csr_src.
__global__ void k_bucket_csr(const unsigned int* __restrict__ bedges,
                             const int* __restrict__ bucket_base,
                             int* __restrict__ rowptr, float* __restrict__ dinv,
                             int* __restrict__ csr_src, int N) {
    __shared__ int hist[THREADS];
    __shared__ int sc[THREADS];
    __shared__ int cur[THREADS];
    int t = threadIdx.x;
    int b = blockIdx.x;
    int base = bucket_base[b];
    int end = bucket_base[b + 1];
    hist[t] = 0;
    __syncthreads();
    for (int i = base + t; i < end; i += THREADS)
        atomicAdd(&hist[bedges[i] & (THREADS - 1)], 1);
    __syncthreads();
    int c = hist[t];
    sc[t] = c;
    __syncthreads();
    for (int off = 1; off < THREADS; off <<= 1) {
        int u = (t >= off) ? sc[t - off] : 0;
        __syncthreads();
        sc[t] += u;
        __syncthreads();
    }
    int excl = sc[t] - c;
    int node = (b << BSH) + t;
    if (node < N) {
        rowptr[node] = base + excl;
        dinv[node] = (float)(1.0 / sqrt((double)(c + 1)));
    }
    cur[t] = excl;
    __syncthreads();
    for (int i = base + t; i < end; i += THREADS) {
        unsigned int u = bedges[i];
        int ln = (int)(u & (THREADS - 1));
        int p = atomicAdd(&cur[ln], 1);
        csr_src[base + p] = (int)(u >> BSH);
    }
}

// Hb1[n][j] = bf16( (sum_k X[n][k] * W1[k][j]) * dinv[n] )   (K=128, J=16)
__global__ void k_gemm1(const float* __restrict__ X, const float* __restrict__ W,
                        const float* __restrict__ dinv, unsigned short* __restrict__ H, int N) {
    __shared__ float Ws[128 * 16];
    for (int i = threadIdx.x; i < 128 * 16; i += blockDim.x) Ws[i] = W[i];
    __syncthreads();
    int row = blockIdx.x * 16 + threadIdx.x / 16;
    int j = threadIdx.x % 16;
    if (row >= N) return;
    const float4* xr4 = (const float4*)(X + (size_t)row * 128);
    float acc = 0.0f;
#pragma unroll
    for (int k4 = 0; k4 < 32; ++k4) {
        float4 xv = xr4[k4];
        acc += xv.x * Ws[(k4 * 4 + 0) * 16 + j];
        acc += xv.y * Ws[(k4 * 4 + 1) * 16 + j];
        acc += xv.z * Ws[(k4 * 4 + 2) * 16 + j];
        acc += xv.w * Ws[(k4 * 4 + 3) * 16 + j];
    }
    H[(size_t)row * 16 + j] = f2bf(acc * dinv[row]);
}

// Pull from bf16 table: t = dinv[n]*(sum_{e->n} Hb[src] + Hb[n]); 4 features/lane.
// MODE 0: fp32 out = t + b          (final layer, pre-pool)
// MODE 1: bf16 out = relu(t+b)*dinv (L1 out, pre-scaled for next pull)
// MODE 2: fp32 out = t              (L2 pre-GEMM aggregate)
template<int F, int MODE>
__global__ void k_pull(const int* __restrict__ rowptr, const int* __restrict__ csr_src,
                       const float* __restrict__ dinv, const unsigned short* __restrict__ Hb,
                       const float* __restrict__ bias, void* __restrict__ outp, int N) {
    const int LPN = F / 4;             // lanes per node
    const int NPB = THREADS / LPN;     // nodes per block
    int node = blockIdx.x * NPB + threadIdx.x / LPN;
    int fq = threadIdx.x % LPN;        // feature quad
    if (node >= N) return;
    int beg = rowptr[node], end = rowptr[node + 1];
    const size_t off = (size_t)4 * fq;
    float4 acc = make_float4(0.f, 0.f, 0.f, 0.f);
    int i = beg;
    for (; i + 4 <= end; i += 4) {
        int s0 = csr_src[i + 0];
        int s1 = csr_src[i + 1];
        int s2 = csr_src[i + 2];
        int s3 = csr_src[i + 3];
        float4 g0 = ldbf4(Hb + (size_t)s0 * F + off);
        float4 g1 = ldbf4(Hb + (size_t)s1 * F + off);
        float4 g2 = ldbf4(Hb + (size_t)s2 * F + off);
        float4 g3 = ldbf4(Hb + (size_t)s3 * F + off);
        acc.x += (g0.x + g1.x) + (g2.x + g3.x);
        acc.y += (g0.y + g1.y) + (g2.y + g3.y);
        acc.z += (g0.z + g1.z) + (g2.z + g3.z);
        acc.w += (g0.w + g1.w) + (g2.w + g3.w);
    }
    for (; i < end; ++i) {
        int s = csr_src[i];
        float4 g = ldbf4(Hb + (size_t)s * F + off);
        acc.x += g.x; acc.y += g.y; acc.z += g.z; acc.w += g.w;
    }
    float4 self = ldbf4(Hb + (size_t)node * F + off);
    float di = dinv[node];
    float4 t;
    t.x = di * (acc.x + self.x);
    t.y = di * (acc.y + self.y);
    t.z = di * (acc.z + self.z);
    t.w = di * (acc.w + self.w);
    if (MODE == 0) {
        float4 o;
        o.x = t.x + bias[4 * fq + 0];
        o.y = t.y + bias[4 * fq + 1];
        o.z = t.z + bias[4 * fq + 2];
        o.w = t.w + bias[4 * fq + 3];
        *(float4*)((float*)outp + (size_t)node * F + off) = o;
    } else if (MODE == 1) {
        float4 v;
        v.x = fmaxf(t.x + bias[4 * fq + 0], 0.f) * di;
        v.y = fmaxf(t.y + bias[4 * fq + 1], 0.f) * di;
        v.z = fmaxf(t.z + bias[4 * fq + 2], 0.f) * di;
        v.w = fmaxf(t.w + bias[4 * fq + 3], 0.f) * di;
        uint2 st;
        st.x = pk2bf(v.x, v.y);
        st.y = pk2bf(v.z, v.w);
        *(uint2*)((unsigned short*)outp + (size_t)node * F + off) = st;
    } else {
        *(float4*)((float*)outp + (size_t)node * F + off) = t;
    }
}

// Register MLP: one thread per node. Hb3[n] = bf16((relu(P2[n]@W2+b2)@W3)*dinv[n])
__global__ __launch_bounds__(256) void k_mlp(const float* __restrict__ P2,
                      const float* __restrict__ W2, const float* __restrict__ b2,
                      const float* __restrict__ W3, const float* __restrict__ dinv,
                      unsigned short* __restrict__ Hb3, int N) {
    __shared__ float W2t[64][16];   // W2t[j][k] = W2[k][j]
    __shared__ float W3t[32][64];   // W3t[m][j] = W3[j][m]
    __shared__ float b2s[64];
    int t = threadIdx.x;
    for (int i = t; i < 64 * 16; i += THREADS) W2t[i / 16][i % 16] = W2[(i % 16) * 64 + (i / 16)];
    for (int i = t; i < 32 * 64; i += THREADS) W3t[i / 64][i % 64] = W3[(i % 64) * 32 + (i / 64)];
    if (t < 64) b2s[t] = b2[t];
    __syncthreads();
    int n = blockIdx.x * THREADS + t;
    if (n >= N) return;
    const float4* pr = (const float4*)(P2 + (size_t)n * 16);
    float4 p0 = pr[0], p1 = pr[1], p2v = pr[2], p3 = pr[3];
    float p[16] = { p0.x, p0.y, p0.z, p0.w, p1.x, p1.y, p1.z, p1.w,
                    p2v.x, p2v.y, p2v.z, p2v.w, p3.x, p3.y, p3.z, p3.w };
    float a[64];
#pragma unroll
    for (int j = 0; j < 64; ++j) {
        const float4* w = (const float4*)W2t[j];  // wave-uniform -> LDS broadcast
        float4 w0 = w[0], w1 = w[1], w2q = w[2], w3q = w[3];
        float acc = b2s[j];
        acc += p[0] * w0.x + p[1] * w0.y + p[2] * w0.z + p[3] * w0.w;
        acc += p[4] * w1.x + p[5] * w1.y + p[6] * w1.z + p[7] * w1.w;
        acc += p[8] * w2q.x + p[9] * w2q.y + p[10] * w2q.z + p[11] * w2q.w;
        acc += p[12] * w3q.x + p[13] * w3q.y + p[14] * w3q.z + p[15] * w3q.w;
        a[j] = fmaxf(acc, 0.0f);
    }
    float di = dinv[n];
    unsigned short* outr = Hb3 + (size_t)n * 32;
#pragma unroll
    for (int m = 0; m < 32; m += 2) {
        float o0 = 0.0f, o1 = 0.0f;
        const float4* wa = (const float4*)W3t[m];
        const float4* wb = (const float4*)W3t[m + 1];
#pragma unroll
        for (int q = 0; q < 16; ++q) {
            float4 va = wa[q], vb = wb[q];
            o0 += a[4 * q] * va.x + a[4 * q + 1] * va.y + a[4 * q + 2] * va.z + a[4 * q + 3] * va.w;
            o1 += a[4 * q] * vb.x + a[4 * q + 1] * vb.y + a[4 * q + 2] * vb.z + a[4 * q + 3] * vb.w;
        }
        *(unsigned int*)(outr + m) = pk2bf(o0 * di, o1 * di);
    }
}

__global__ void k_zero_f(float* p, int n) {
    int i = blockIdx.x * blockDim.x + threadIdx.x;
    if (i < n) p[i] = 0.0f;
}

// Parallel segmented pooling: block owns POOL_C contiguous nodes. batch is
// sorted, so each thread's run crosses few graph boundaries -> run-length
// accumulate in a register, atomicAdd to sums only on boundary.
__global__ void k_pool_part(const float* __restrict__ h3, const int* __restrict__ batch,
                            float* __restrict__ sums, int N) {
    int f = threadIdx.x & 31;
    int sub = threadIdx.x >> 5;   // 8 node-lanes
    int n0 = blockIdx.x * POOL_C;
    int n1 = min(N, n0 + POOL_C);
    float acc = 0.0f;
    int curg = -1;
    for (int n = n0 + sub; n < n1; n += 8) {
        int g = batch[n];
        if (g != curg) {
            if (curg >= 0) atomicAdd(&sums[curg * 32 + f], acc);
            acc = 0.0f;
            curg = g;
        }
        acc += h3[(size_t)n * 32 + f];
    }
    if (curg >= 0) atomicAdd(&sums[curg * 32 + f], acc);
}

// Head: cnt via binary search on sorted batch; a=relu(pooled@Wa+ba); out=tanh(a@Wo+bo)
__global__ void k_head(const float* __restrict__ sums, const int* __restrict__ batch, int N,
                       const float* __restrict__ Wa, const float* __restrict__ ba,
                       const float* __restrict__ Wo, const float* __restrict__ bo,
                       float* __restrict__ out) {
    int g = blockIdx.x;
    int j = threadIdx.x;  // 64 threads
    // every thread does the same two binary searches (trivial, no divergence)
    int lo = 0, hi = N;
    while (lo < hi) { int m = (lo + hi) >> 1; if (batch[m] < g) lo = m + 1; else hi = m; }
    int start = lo;
    lo = start; hi = N;
    while (lo < hi) { int m = (lo + hi) >> 1; if (batch[m] < g + 1) lo = m + 1; else hi = m; }
    int cnt = lo - start;
    float inv = 1.0f / (float)(cnt > 0 ? cnt : 1);

    __shared__ float p[32];
    __shared__ float a[64];
    if (j < 32) p[j] = sums[g * 32 + j] * inv;
    __syncthreads();
    float acc = ba[j];
#pragma unroll
    for (int k = 0; k < 32; ++k) acc += p[k] * Wa[k * 64 + j];
    a[j] = fmaxf(acc, 0.0f);
    __syncthreads();
    if (j < 32) {
        float acc2 = bo[j];
#pragma unroll
        for (int k = 0; k < 64; ++k) acc2 += a[k] * Wo[k * 32 + j];
        out[g * 32 + j] = tanhf(acc2);
    }
}

static inline int cdiv(long long a, int b) { return (int)((a + b - 1) / b); }
static inline size_t align256(size_t x) { return (x + 255) & ~(size_t)255; }

extern "C" void kernel_launch(void* const* d_in, const int* in_sizes, int n_in,
                              void* d_out, int out_size, void* d_ws, size_t ws_size,
                              hipStream_t stream) {
    const float* x     = (const float*)d_in[0];
    const int*   edge  = (const int*)d_in[1];
    const int*   batch = (const int*)d_in[2];
    const float* W1 = (const float*)d_in[3];  const float* b1 = (const float*)d_in[4];
    const float* W2 = (const float*)d_in[5];  const float* b2 = (const float*)d_in[6];
    const float* W3 = (const float*)d_in[7];  const float* b3 = (const float*)d_in[8];
    const float* Wa = (const float*)d_in[9];  const float* ba = (const float*)d_in[10];
    const float* Wo = (const float*)d_in[11]; const float* bo = (const float*)d_in[12];

    const int E = in_sizes[1] / 2;
    const int N = in_sizes[2];
    const int G = 64;
    const int NB = cdiv(N, 1 << BSH);     // 391
    const int NCH = cdiv(E, CH_E);        // 1563

    const int* srcp = edge;
    const int* dstp = edge + E;

    // Workspace
    char* base = (char*)d_ws;
    size_t off = 0;
    float* dinv   = (float*)(base + off); off = align256(off + sizeof(float) * N);
    unsigned short* lp16 = (unsigned short*)(base + off); off = align256(off + sizeof(short) * E);
    int* cnt_mat  = (int*)(base + off); off = align256(off + sizeof(int) * (size_t)NB * NCH);
    int* offs_mat = (int*)(base + off); off = align256(off + sizeof(int) * (size_t)NB * NCH);
    int* btot     = (int*)(base + off); off = align256(off + sizeof(int) * (NB + 1));
    int* bbase    = (int*)(base + off); off = align256(off + sizeof(int) * (NB + 1));
    unsigned int* bedges = (unsigned int*)(base + off); off = align256(off + sizeof(int) * E);
    int* rowptr   = (int*)(base + off); off = align256(off + sizeof(int) * (N + 1));
    int* csr_src  = (int*)(base + off); off = align256(off + sizeof(int) * E);
    unsigned short* Hb1 = (unsigned short*)(base + off); off = align256(off + sizeof(short) * (size_t)N * 16);
    unsigned short* Hb2 = (unsigned short*)(base + off); off = align256(off + sizeof(short) * (size_t)N * 16);
    float* P2     = (float*)(base + off); off = align256(off + sizeof(float) * (size_t)N * 16);
    unsigned short* Hb3 = (unsigned short*)(base + off); off = align256(off + sizeof(short) * (size_t)N * 32);
    float* h3     = (float*)(base + off); off = align256(off + sizeof(float) * (size_t)N * 32);
    float* sums   = (float*)(base + off); off = align256(off + sizeof(float) * G * 32);

    // ---- Atomic-free binning -> bucket-sorted bedges ----
    k_countA<<<NCH, THREADS, 0, stream>>>(dstp, lp16, cnt_mat, E, NB, NCH);
    k_sumK1<<<NB, THREADS, 0, stream>>>(cnt_mat, btot, NCH);
    k_scanK2<<<1, MAXNB, 0, stream>>>(btot, bbase, NB, E);
    k_scanK3<<<NB, THREADS, 0, stream>>>(cnt_mat, bbase, offs_mat, NCH);
    k_scatter2<<<NCH, THREADS, 0, stream>>>(srcp, dstp, lp16, offs_mat, bedges, E, NB, NCH);

    // ---- CSR (rowptr, csr_src, dinv) from bucket-sorted edges ----
    k_bucket_csr<<<NB, THREADS, 0, stream>>>(bedges, bbase, rowptr, dinv, csr_src, N);

    // ---- Layer 1: Hb1 = bf16((x@W1)*dinv); pull16 -> Hb2 = bf16(relu(.+b1)*dinv) ----
    k_gemm1<<<cdiv(N, 16), THREADS, 0, stream>>>(x, W1, dinv, Hb1, N);
    k_pull<16, 1><<<cdiv(N, 64), THREADS, 0, stream>>>(rowptr, csr_src, dinv, Hb1, b1, Hb2, N);

    // ---- Layer 2 aggregate at input width: P2 = pull16(Hb2) ----
    k_pull<16, 2><<<cdiv(N, 64), THREADS, 0, stream>>>(rowptr, csr_src, dinv, Hb2, b1 /*unused*/, P2, N);

    // ---- Fused node MLP: Hb3 = bf16((relu(P2@W2+b2)@W3)*dinv) ----
    k_mlp<<<cdiv(N, THREADS), THREADS, 0, stream>>>(P2, W2, b2, W3, dinv, Hb3, N);

    // ---- Layer 3 aggregate: h3 = pull32(Hb3) + b3 ----
    k_pull<32, 0><<<cdiv(N, 32), THREADS, 0, stream>>>(rowptr, csr_src, dinv, Hb3, b3, h3, N);

    // ---- Pool (parallel, run-length atomics) + head ----
    k_zero_f<<<cdiv(G * 32, THREADS), THREADS, 0, stream>>>(sums, G * 32);
    k_pool_part<<<cdiv(N, POOL_C), THREADS, 0, stream>>>(h3, batch, sums, N);
    k_head<<<G, 64, 0, stream>>>(sums, batch, N, Wa, ba, Wo, bo, (float*)d_out);
}

// Round 9
// 387.177 us; speedup vs baseline: 4.2437x; 1.0145x over previous
//
#include <hip/hip_runtime.h>
#include <hip/hip_bf16.h>
#include <math.h>

// ActorGNN R9: R8 + row-per-thread gemm1 (W^T in LDS), 16B-gather pulls
// (8 features/lane), 512-thread bucket_csr. N=100000, E=3200000, G=64.

#define THREADS 256
#define TCSR 512              // threads for k_bucket_csr
#define BSH 8                 // bucket shift: bucket = dst>>8 (<=256 nodes each)
#define MAXNB 512             // LDS histogram capacity (N <= 131072)
#define CH_E 2048             // edges per chunk in binning passes
#define CPT 8                 // chunks per thread in k_scanK3 (NCH <= 2048)
#define POOL_C 512            // nodes per pooling block

// ---- bf16 helpers ----
__device__ inline unsigned short f2bf(float f) {
    unsigned int u = __float_as_uint(f);
    return (unsigned short)((u + 0x7fffu + ((u >> 16) & 1u)) >> 16);  // RNE
}
__device__ inline unsigned int pk2bf(float a, float b) {
    return (unsigned int)f2bf(a) | ((unsigned int)f2bf(b) << 16);
}
__device__ inline float bflo(unsigned int u) { return __uint_as_float(u << 16); }
__device__ inline float bfhi(unsigned int u) { return __uint_as_float(u & 0xffff0000u); }
__device__ inline void unpk8(const uint4 u, float* f) {
    f[0] = bflo(u.x); f[1] = bfhi(u.x); f[2] = bflo(u.y); f[3] = bfhi(u.y);
    f[4] = bflo(u.z); f[5] = bfhi(u.z); f[6] = bflo(u.w); f[7] = bfhi(u.w);
}

// ---- Atomic-free binning: pass A counts + records local position ----
__global__ void k_countA(const int* __restrict__ dst, unsigned short* __restrict__ lp16,
                         int* __restrict__ cnt_mat, int E, int NB, int NCH) {
    __shared__ int hist[MAXNB];
    int t = threadIdx.x, chunk = blockIdx.x;
    for (int h = t; h < NB; h += THREADS) hist[h] = 0;
    __syncthreads();
    int e0 = chunk * CH_E, e1 = min(E, e0 + CH_E);
    for (int e = e0 + t; e < e1; e += THREADS) {
        int h = dst[e] >> BSH;
        int lp = atomicAdd(&hist[h], 1);
        lp16[e] = (unsigned short)lp;
    }
    __syncthreads();
    for (int h = t; h < NB; h += THREADS) cnt_mat[(size_t)h * NCH + chunk] = hist[h];
}

// K1: bucket totals
__global__ void k_sumK1(const int* __restrict__ cnt_mat, int* __restrict__ bucket_tot, int NCH) {
    __shared__ int red[THREADS];
    int b = blockIdx.x, t = threadIdx.x;
    int s = 0;
    for (int c = t; c < NCH; c += THREADS) s += cnt_mat[(size_t)b * NCH + c];
    red[t] = s;
    __syncthreads();
    for (int off = THREADS / 2; off > 0; off >>= 1) {
        if (t < off) red[t] += red[t + off];
        __syncthreads();
    }
    if (t == 0) bucket_tot[b] = red[0];
}

// K2: single block exclusive scan of NB bucket totals -> bucket_base; [NB]=E
__global__ void k_scanK2(const int* __restrict__ bucket_tot, int* __restrict__ bucket_base,
                         int NB, int E) {
    __shared__ int sh[MAXNB];
    int t = threadIdx.x;  // 512
    int v = (t < NB) ? bucket_tot[t] : 0;
    sh[t] = v;
    __syncthreads();
    for (int off = 1; off < MAXNB; off <<= 1) {
        int u = (t >= off) ? sh[t - off] : 0;
        __syncthreads();
        sh[t] += u;
        __syncthreads();
    }
    if (t < NB) bucket_base[t] = sh[t] - v;
    if (t == 0) bucket_base[NB] = E;
}

// K3: per-bucket exclusive scan over chunks + bucket base -> offs_mat
__global__ void k_scanK3(const int* __restrict__ cnt_mat, const int* __restrict__ bucket_base,
                         int* __restrict__ offs_mat, int NCH) {
    __shared__ int sh[THREADS];
    int b = blockIdx.x, t = threadIdx.x;
    int c0 = t * CPT;
    int v[CPT];
    int s = 0;
#pragma unroll
    for (int k = 0; k < CPT; ++k) {
        int c = c0 + k;
        v[k] = (c < NCH) ? cnt_mat[(size_t)b * NCH + c] : 0;
        s += v[k];
    }
    sh[t] = s;
    __syncthreads();
    for (int off = 1; off < THREADS; off <<= 1) {
        int u = (t >= off) ? sh[t - off] : 0;
        __syncthreads();
        sh[t] += u;
        __syncthreads();
    }
    int run = bucket_base[b] + sh[t] - s;
#pragma unroll
    for (int k = 0; k < CPT; ++k) {
        int c = c0 + k;
        if (c < NCH) { offs_mat[(size_t)b * NCH + c] = run; run += v[k]; }
    }
}

// Pass B: deterministic scatter. pos = offs[bucket][chunk] + lp. No atomics.
__global__ void k_scatter2(const int* __restrict__ src, const int* __restrict__ dst,
                           const unsigned short* __restrict__ lp16,
                           const int* __restrict__ offs_mat,
                           unsigned int* __restrict__ bedges, int E, int NB, int NCH) {
    __shared__ int offs[MAXNB];
    int t = threadIdx.x, chunk = blockIdx.x;
    for (int h = t; h < NB; h += THREADS) offs[h] = offs_mat[(size_t)h * NCH + chunk];
    __syncthreads();
    int e0 = chunk * CH_E, e1 = min(E, e0 + CH_E);
    for (int e = e0 + t; e < e1; e += THREADS) {
        int d = dst[e];
        int h = d >> BSH;
        int pos = offs[h] + (int)lp16[e];
        bedges[pos] = ((unsigned int)src[e] << BSH) | (unsigned int)(d & ((1 << BSH) - 1));
    }
}

// Block = bucket (<=256 nodes), 512 threads: LDS histogram -> rowptr, dinv;
// place srcs into csr_src.
__global__ void k_bucket_csr(const unsigned int* __restrict__ bedges,
                             const int* __restrict__ bucket_base,
                             int* __restrict__ rowptr, float* __restrict__ dinv,
                             int* __restrict__ csr_src, int N) {
    __shared__ int hist[256];
    __shared__ int sc[256];
    __shared__ int cur[256];
    int t = threadIdx.x;   // 0..511
    int b = blockIdx.x;
    int base = bucket_base[b];
    int end = bucket_base[b + 1];
    if (t < 256) hist[t] = 0;
    __syncthreads();
    for (int i = base + t; i < end; i += TCSR)
        atomicAdd(&hist[bedges[i] & 255], 1);
    __syncthreads();
    int c = 0;
    if (t < 256) { c = hist[t]; sc[t] = c; }
    __syncthreads();
    for (int off = 1; off < 256; off <<= 1) {
        int u = (t >= off && t < 256) ? sc[t - off] : 0;
        __syncthreads();
        if (t < 256) sc[t] += u;
        __syncthreads();
    }
    if (t < 256) {
        int excl = sc[t] - c;
        int node = (b << BSH) + t;
        if (node < N) {
            rowptr[node] = base + excl;
            dinv[node] = (float)(1.0 / sqrt((double)(c + 1)));
        }
        cur[t] = excl;
    }
    __syncthreads();
    for (int i = base + t; i < end; i += TCSR) {
        unsigned int u = bedges[i];
        int ln = (int)(u & 255);
        int p = atomicAdd(&cur[ln], 1);
        csr_src[base + p] = (int)(u >> BSH);
    }
}

// Row-per-thread GEMM: Hb1[n] = bf16((x[n] @ W1) * dinv[n]); W1^T staged in LDS.
__global__ __launch_bounds__(256) void k_gemm1(const float* __restrict__ X,
                        const float* __restrict__ W,
                        const float* __restrict__ dinv, unsigned short* __restrict__ H, int N) {
    __shared__ float Wt[16 * 128];   // Wt[j][k] = W[k][j]
    int t = threadIdx.x;
    for (int i = t; i < 16 * 128; i += THREADS) {
        int j = i >> 7, k = i & 127;
        Wt[i] = W[k * 16 + j];
    }
    __syncthreads();
    int row = blockIdx.x * THREADS + t;
    if (row >= N) return;
    const float4* xr = (const float4*)(X + (size_t)row * 128);
    float acc[16];
#pragma unroll
    for (int j = 0; j < 16; ++j) acc[j] = 0.0f;
#pragma unroll 4
    for (int k4 = 0; k4 < 32; ++k4) {
        float4 xv = xr[k4];
#pragma unroll
        for (int j = 0; j < 16; ++j) {
            const float4 wv = *(const float4*)&Wt[j * 128 + k4 * 4];  // uniform -> broadcast
            acc[j] += xv.x * wv.x + xv.y * wv.y + xv.z * wv.z + xv.w * wv.w;
        }
    }
    float di = dinv[row];
    uint4 oa, ob;
    oa.x = pk2bf(acc[0] * di, acc[1] * di);
    oa.y = pk2bf(acc[2] * di, acc[3] * di);
    oa.z = pk2bf(acc[4] * di, acc[5] * di);
    oa.w = pk2bf(acc[6] * di, acc[7] * di);
    ob.x = pk2bf(acc[8] * di, acc[9] * di);
    ob.y = pk2bf(acc[10] * di, acc[11] * di);
    ob.z = pk2bf(acc[12] * di, acc[13] * di);
    ob.w = pk2bf(acc[14] * di, acc[15] * di);
    uint4* outr = (uint4*)(H + (size_t)row * 16);
    outr[0] = oa;
    outr[1] = ob;
}

// Pull from bf16 table: 8 features per lane (16B gathers).
// t = dinv[n]*(sum_{e->n} Hb[src] + Hb[n])
// MODE 0: fp32 out = t + b          (final layer, pre-pool)
// MODE 1: bf16 out = relu(t+b)*dinv (L1 out, pre-scaled for next pull)
// MODE 2: fp32 out = t              (L2 pre-GEMM aggregate)
template<int F, int MODE>
__global__ void k_pull(const int* __restrict__ rowptr, const int* __restrict__ csr_src,
                       const float* __restrict__ dinv, const unsigned short* __restrict__ Hb,
                       const float* __restrict__ bias, void* __restrict__ outp, int N) {
    const int LPN = F / 8;             // lanes per node (2 or 4)
    const int NPB = THREADS / LPN;     // nodes per block
    int node = blockIdx.x * NPB + threadIdx.x / LPN;
    int fo = (threadIdx.x % LPN) * 8;  // feature offset
    if (node >= N) return;
    int beg = rowptr[node], end = rowptr[node + 1];
    float acc[8] = {0.f, 0.f, 0.f, 0.f, 0.f, 0.f, 0.f, 0.f};
    int i = beg;
    for (; i + 4 <= end; i += 4) {
        int s0 = csr_src[i + 0];
        int s1 = csr_src[i + 1];
        int s2 = csr_src[i + 2];
        int s3 = csr_src[i + 3];
        uint4 g0 = *(const uint4*)(Hb + (size_t)s0 * F + fo);
        uint4 g1 = *(const uint4*)(Hb + (size_t)s1 * F + fo);
        uint4 g2 = *(const uint4*)(Hb + (size_t)s2 * F + fo);
        uint4 g3 = *(const uint4*)(Hb + (size_t)s3 * F + fo);
        float f0[8], f1[8], f2[8], f3[8];
        unpk8(g0, f0); unpk8(g1, f1); unpk8(g2, f2); unpk8(g3, f3);
#pragma unroll
        for (int j = 0; j < 8; ++j) acc[j] += (f0[j] + f1[j]) + (f2[j] + f3[j]);
    }
    for (; i < end; ++i) {
        int s = csr_src[i];
        uint4 g = *(const uint4*)(Hb + (size_t)s * F + fo);
        float f[8];
        unpk8(g, f);
#pragma unroll
        for (int j = 0; j < 8; ++j) acc[j] += f[j];
    }
    uint4 gs = *(const uint4*)(Hb + (size_t)node * F + fo);
    float sf[8];
    unpk8(gs, sf);
    float di = dinv[node];
    float tv[8];
#pragma unroll
    for (int j = 0; j < 8; ++j) tv[j] = di * (acc[j] + sf[j]);
    if (MODE == 0) {
        float* of = (float*)outp + (size_t)node * F + fo;
        float4 o0, o1;
        o0.x = tv[0] + bias[fo + 0]; o0.y = tv[1] + bias[fo + 1];
        o0.z = tv[2] + bias[fo + 2]; o0.w = tv[3] + bias[fo + 3];
        o1.x = tv[4] + bias[fo + 4]; o1.y = tv[5] + bias[fo + 5];
        o1.z = tv[6] + bias[fo + 6]; o1.w = tv[7] + bias[fo + 7];
        ((float4*)of)[0] = o0; ((float4*)of)[1] = o1;
    } else if (MODE == 1) {
        float w[8];
#pragma unroll
        for (int j = 0; j < 8; ++j) w[j] = fmaxf(tv[j] + bias[fo + j], 0.0f) * di;
        uint4 st;
        st.x = pk2bf(w[0], w[1]); st.y = pk2bf(w[2], w[3]);
        st.z = pk2bf(w[4], w[5]); st.w = pk2bf(w[6], w[7]);
        *(uint4*)((unsigned short*)outp + (size_t)node * F + fo) = st;
    } else {
        float* of = (float*)outp + (size_t)node * F + fo;
        float4 o0, o1;
        o0.x = tv[0]; o0.y = tv[1]; o0.z = tv[2]; o0.w = tv[3];
        o1.x = tv[4]; o1.y = tv[5]; o1.z = tv[6]; o1.w = tv[7];
        ((float4*)of)[0] = o0; ((float4*)of)[1] = o1;
    }
}

// Register MLP: one thread per node. Hb3[n] = bf16((relu(P2[n]@W2+b2)@W3)*dinv[n])
__global__ __launch_bounds__(256) void k_mlp(const float* __restrict__ P2,
                      const float* __restrict__ W2, const float* __restrict__ b2,
                      const float* __restrict__ W3, const float* __restrict__ dinv,
                      unsigned short* __restrict__ Hb3, int N) {
    __shared__ float W2t[64][16];   // W2t[j][k] = W2[k][j]
    __shared__ float W3t[32][64];   // W3t[m][j] = W3[j][m]
    __shared__ float b2s[64];
    int t = threadIdx.x;
    for (int i = t; i < 64 * 16; i += THREADS) W2t[i / 16][i % 16] = W2[(i % 16) * 64 + (i / 16)];
    for (int i = t; i < 32 * 64; i += THREADS) W3t[i / 64][i % 64] = W3[(i % 64) * 32 + (i / 64)];
    if (t < 64) b2s[t] = b2[t];
    __syncthreads();
    int n = blockIdx.x * THREADS + t;
    if (n >= N) return;
    const float4* pr = (const float4*)(P2 + (size_t)n * 16);
    float4 p0 = pr[0], p1 = pr[1], p2v = pr[2], p3 = pr[3];
    float p[16] = { p0.x, p0.y, p0.z, p0.w, p1.x, p1.y, p1.z, p1.w,
                    p2v.x, p2v.y, p2v.z, p2v.w, p3.x, p3.y, p3.z, p3.w };
    float a[64];
#pragma unroll
    for (int j = 0; j < 64; ++j) {
        const float4* w = (const float4*)W2t[j];  // wave-uniform -> LDS broadcast
        float4 w0 = w[0], w1 = w[1], w2q = w[2], w3q = w[3];
        float acc = b2s[j];
        acc += p[0] * w0.x + p[1] * w0.y + p[2] * w0.z + p[3] * w0.w;
        acc += p[4] * w1.x + p[5] * w1.y + p[6] * w1.z + p[7] * w1.w;
        acc += p[8] * w2q.x + p[9] * w2q.y + p[10] * w2q.z + p[11] * w2q.w;
        acc += p[12] * w3q.x + p[13] * w3q.y + p[14] * w3q.z + p[15] * w3q.w;
        a[j] = fmaxf(acc, 0.0f);
    }
    float di = dinv[n];
    unsigned short* outr = Hb3 + (size_t)n * 32;
#pragma unroll
    for (int m = 0; m < 32; m += 2) {
        float o0 = 0.0f, o1 = 0.0f;
        const float4* wa = (const float4*)W3t[m];
        const float4* wb = (const float4*)W3t[m + 1];
#pragma unroll
        for (int q = 0; q < 16; ++q) {
            float4 va = wa[q], vb = wb[q];
            o0 += a[4 * q] * va.x + a[4 * q + 1] * va.y + a[4 * q + 2] * va.z + a[4 * q + 3] * va.w;
            o1 += a[4 * q] * vb.x + a[4 * q + 1] * vb.y + a[4 * q + 2] * vb.z + a[4 * q + 3] * vb.w;
        }
        *(unsigned int*)(outr + m) = pk2bf(o0 * di, o1 * di);
    }
}

__global__ void k_zero_f(float* p, int n) {
    int i = blockIdx.x * blockDim.x + threadIdx.x;
    if (i < n) p[i] = 0.0f;
}

// Parallel segmented pooling: run-length accumulate, atomic on graph boundary.
__global__ void k_pool_part(const float* __restrict__ h3, const int* __restrict__ batch,
                            float* __restrict__ sums, int N) {
    int f = threadIdx.x & 31;
    int sub = threadIdx.x >> 5;   // 8 node-lanes
    int n0 = blockIdx.x * POOL_C;
    int n1 = min(N, n0 + POOL_C);
    float acc = 0.0f;
    int curg = -1;
    for (int n = n0 + sub; n < n1; n += 8) {
        int g = batch[n];
        if (g != curg) {
            if (curg >= 0) atomicAdd(&sums[curg * 32 + f], acc);
            acc = 0.0f;
            curg = g;
        }
        acc += h3[(size_t)n * 32 + f];
    }
    if (curg >= 0) atomicAdd(&sums[curg * 32 + f], acc);
}

// Head: cnt via binary search; a=relu(pooled@Wa+ba); out=tanh(a@Wo+bo)
__global__ void k_head(const float* __restrict__ sums, const int* __restrict__ batch, int N,
                       const float* __restrict__ Wa, const float* __restrict__ ba,
                       const float* __restrict__ Wo, const float* __restrict__ bo,
                       float* __restrict__ out) {
    int g = blockIdx.x;
    int j = threadIdx.x;  // 64 threads
    int lo = 0, hi = N;
    while (lo < hi) { int m = (lo + hi) >> 1; if (batch[m] < g) lo = m + 1; else hi = m; }
    int start = lo;
    lo = start; hi = N;
    while (lo < hi) { int m = (lo + hi) >> 1; if (batch[m] < g + 1) lo = m + 1; else hi = m; }
    int cnt = lo - start;
    float inv = 1.0f / (float)(cnt > 0 ? cnt : 1);

    __shared__ float p[32];
    __shared__ float a[64];
    if (j < 32) p[j] = sums[g * 32 + j] * inv;
    __syncthreads();
    float acc = ba[j];
#pragma unroll
    for (int k = 0; k < 32; ++k) acc += p[k] * Wa[k * 64 + j];
    a[j] = fmaxf(acc, 0.0f);
    __syncthreads();
    if (j < 32) {
        float acc2 = bo[j];
#pragma unroll
        for (int k = 0; k < 64; ++k) acc2 += a[k] * Wo[k * 32 + j];
        out[g * 32 + j] = tanhf(acc2);
    }
}

static inline int cdiv(long long a, int b) { return (int)((a + b - 1) / b); }
static inline size_t align256(size_t x) { return (x + 255) & ~(size_t)255; }

extern "C" void kernel_launch(void* const* d_in, const int* in_sizes, int n_in,
                              void* d_out, int out_size, void* d_ws, size_t ws_size,
                              hipStream_t stream) {
    const float* x     = (const float*)d_in[0];
    const int*   edge  = (const int*)d_in[1];
    const int*   batch = (const int*)d_in[2];
    const float* W1 = (const float*)d_in[3];  const float* b1 = (const float*)d_in[4];
    const float* W2 = (const float*)d_in[5];  const float* b2 = (const float*)d_in[6];
    const float* W3 = (const float*)d_in[7];  const float* b3 = (const float*)d_in[8];
    const float* Wa = (const float*)d_in[9];  const float* ba = (const float*)d_in[10];
    const float* Wo = (const float*)d_in[11]; const float* bo = (const float*)d_in[12];

    const int E = in_sizes[1] / 2;
    const int N = in_sizes[2];
    const int G = 64;
    const int NB = cdiv(N, 1 << BSH);     // 391
    const int NCH = cdiv(E, CH_E);        // 1563

    const int* srcp = edge;
    const int* dstp = edge + E;

    // Workspace
    char* base = (char*)d_ws;
    size_t off = 0;
    float* dinv   = (float*)(base + off); off = align256(off + sizeof(float) * N);
    unsigned short* lp16 = (unsigned short*)(base + off); off = align256(off + sizeof(short) * E);
    int* cnt_mat  = (int*)(base + off); off = align256(off + sizeof(int) * (size_t)NB * NCH);
    int* offs_mat = (int*)(base + off); off = align256(off + sizeof(int) * (size_t)NB * NCH);
    int* btot     = (int*)(base + off); off = align256(off + sizeof(int) * (NB + 1));
    int* bbase    = (int*)(base + off); off = align256(off + sizeof(int) * (NB + 1));
    unsigned int* bedges = (unsigned int*)(base + off); off = align256(off + sizeof(int) * E);
    int* rowptr   = (int*)(base + off); off = align256(off + sizeof(int) * (N + 1));
    int* csr_src  = (int*)(base + off); off = align256(off + sizeof(int) * E);
    unsigned short* Hb1 = (unsigned short*)(base + off); off = align256(off + sizeof(short) * (size_t)N * 16);
    unsigned short* Hb2 = (unsigned short*)(base + off); off = align256(off + sizeof(short) * (size_t)N * 16);
    float* P2     = (float*)(base + off); off = align256(off + sizeof(float) * (size_t)N * 16);
    unsigned short* Hb3 = (unsigned short*)(base + off); off = align256(off + sizeof(short) * (size_t)N * 32);
    float* h3     = (float*)(base + off); off = align256(off + sizeof(float) * (size_t)N * 32);
    float* sums   = (float*)(base + off); off = align256(off + sizeof(float) * G * 32);

    // ---- Atomic-free binning -> bucket-sorted bedges ----
    k_countA<<<NCH, THREADS, 0, stream>>>(dstp, lp16, cnt_mat, E, NB, NCH);
    k_sumK1<<<NB, THREADS, 0, stream>>>(cnt_mat, btot, NCH);
    k_scanK2<<<1, MAXNB, 0, stream>>>(btot, bbase, NB, E);
    k_scanK3<<<NB, THREADS, 0, stream>>>(cnt_mat, bbase, offs_mat, NCH);
    k_scatter2<<<NCH, THREADS, 0, stream>>>(srcp, dstp, lp16, offs_mat, bedges, E, NB, NCH);

    // ---- CSR (rowptr, csr_src, dinv) from bucket-sorted edges ----
    k_bucket_csr<<<NB, TCSR, 0, stream>>>(bedges, bbase, rowptr, dinv, csr_src, N);

    // ---- Layer 1: Hb1 = bf16((x@W1)*dinv); pull16 -> Hb2 = bf16(relu(.+b1)*dinv) ----
    k_gemm1<<<cdiv(N, THREADS), THREADS, 0, stream>>>(x, W1, dinv, Hb1, N);
    k_pull<16, 1><<<cdiv(N, 128), THREADS, 0, stream>>>(rowptr, csr_src, dinv, Hb1, b1, Hb2, N);

    // ---- Layer 2 aggregate at input width: P2 = pull16(Hb2) ----
    k_pull<16, 2><<<cdiv(N, 128), THREADS, 0, stream>>>(rowptr, csr_src, dinv, Hb2, b1 /*unused*/, P2, N);

    // ---- Fused node MLP: Hb3 = bf16((relu(P2@W2+b2)@W3)*dinv) ----
    k_mlp<<<cdiv(N, THREADS), THREADS, 0, stream>>>(P2, W2, b2, W3, dinv, Hb3, N);

    // ---- Layer 3 aggregate: h3 = pull32(Hb3) + b3 ----
    k_pull<32, 0><<<cdiv(N, 64), THREADS, 0, stream>>>(rowptr, csr_src, dinv, Hb3, b3, h3, N);

    // ---- Pool (parallel, run-length atomics) + head ----
    k_zero_f<<<cdiv(G * 32, THREADS), THREADS, 0, stream>>>(sums, G * 32);
    k_pool_part<<<cdiv(N, POOL_C), THREADS, 0, stream>>>(h3, batch, sums, N);
    k_head<<<G, 64, 0, stream>>>(sums, batch, N, Wa, ba, Wo, bo, (float*)d_out);
}